// Round 1
// baseline (585.916 us; speedup 1.0000x reference)
//
#include <hip/hip_runtime.h>
#include <math.h>

#define B_ 64
#define T_ 577
#define E_ 768
#define H_ 64
#define N_ 576
#define GW_ 24

// -------------------- Kernel 1: x@[wq|wk|wv] + LN(q,k) + alpha/sigma --------------------
// grid 577 blocks (64 rows each, 577*64 == B*T exactly), 256 threads.
__global__ __launch_bounds__(256) void qkv_ln_kernel(
    const float* __restrict__ x,
    const float* __restrict__ wq, const float* __restrict__ wk, const float* __restrict__ wv,
    const float* __restrict__ qg, const float* __restrict__ qb,
    const float* __restrict__ kg, const float* __restrict__ kb,
    const float* __restrict__ wsig, const float* __restrict__ bsig,
    const float* __restrict__ walp, const float* __restrict__ balp,
    float* __restrict__ qo, float* __restrict__ ko, float* __restrict__ vo,
    float* __restrict__ alo, float* __restrict__ sxo, float* __restrict__ syo)
{
  // union: stage (xs 64x33 | wsm 32x192) aliased with C tile 64x193 (+stats)
  __shared__ __align__(16) float smem[64*193 + 256];
  float (*xs)[33]   = (float (*)[33])smem;                 // 2112 floats
  float (*wsm)[192] = (float (*)[192])(smem + 2112);       // 6144 floats (16B-aligned offset)
  float (*Cs)[193]  = (float (*)[193])smem;                // 12352 floats (aliases stage bufs)
  float* mu_q = smem + 64*193;
  float* rs_q = mu_q + 64;
  float* mu_k = rs_q + 64;
  float* rs_k = mu_k + 64;

  const int tid = threadIdx.x;
  const int tx = tid & 15;
  const int ty = tid >> 4;
  const int rowbase = blockIdx.x << 6;

  float acc[4][12];
  #pragma unroll
  for (int r = 0; r < 4; ++r)
    #pragma unroll
    for (int j = 0; j < 12; ++j) acc[r][j] = 0.f;

  for (int kc = 0; kc < E_; kc += 32) {
    __syncthreads();
    // x tile: 64 rows x 32 cols, float4 global loads
    #pragma unroll
    for (int i = 0; i < 2; ++i) {
      int s = tid + 256*i;          // 0..511
      int r = s >> 3, c4 = s & 7;
      float4 val = *(const float4*)(x + (size_t)(rowbase + r)*E_ + kc + c4*4);
      xs[r][c4*4+0] = val.x; xs[r][c4*4+1] = val.y;
      xs[r][c4*4+2] = val.z; xs[r][c4*4+3] = val.w;
    }
    // weight tiles: 32 rows x 64 cols each of wq/wk/wv -> wsm[kk][0|64|128 + c]
    {
      int kk0 = tid >> 4,        c40 = tid & 15;
      int kk1 = (tid + 256) >> 4, c41 = tid & 15;
      *(float4*)&wsm[kk0][  0 + c40*4] = *(const float4*)(wq + (size_t)(kc+kk0)*H_ + c40*4);
      *(float4*)&wsm[kk1][  0 + c41*4] = *(const float4*)(wq + (size_t)(kc+kk1)*H_ + c41*4);
      *(float4*)&wsm[kk0][ 64 + c40*4] = *(const float4*)(wk + (size_t)(kc+kk0)*H_ + c40*4);
      *(float4*)&wsm[kk1][ 64 + c41*4] = *(const float4*)(wk + (size_t)(kc+kk1)*H_ + c41*4);
      *(float4*)&wsm[kk0][128 + c40*4] = *(const float4*)(wv + (size_t)(kc+kk0)*H_ + c40*4);
      *(float4*)&wsm[kk1][128 + c41*4] = *(const float4*)(wv + (size_t)(kc+kk1)*H_ + c41*4);
    }
    __syncthreads();
    #pragma unroll 4
    for (int kk = 0; kk < 32; ++kk) {
      float xv[4];
      #pragma unroll
      for (int r = 0; r < 4; ++r) xv[r] = xs[ty*4 + r][kk];
      float wv_[12];
      #pragma unroll
      for (int j = 0; j < 12; ++j) wv_[j] = wsm[kk][tx + 16*j];
      #pragma unroll
      for (int r = 0; r < 4; ++r)
        #pragma unroll
        for (int j = 0; j < 12; ++j)
          acc[r][j] += xv[r] * wv_[j];
    }
  }
  __syncthreads();   // all LDS reads done before aliasing as C tile
  #pragma unroll
  for (int r = 0; r < 4; ++r)
    #pragma unroll
    for (int j = 0; j < 12; ++j)
      Cs[ty*4 + r][tx + 16*j] = acc[r][j];
  __syncthreads();

  // per-row stats + heads (one thread per row; cols 0..63=q, 64..127=k, 128..191=v)
  if (tid < 64) {
    float s = 0.f;
    for (int h = 0; h < 64; ++h) s += Cs[tid][h];
    float mu = s * (1.f/64.f);
    float vs = 0.f;
    for (int h = 0; h < 64; ++h) { float d = Cs[tid][h] - mu; vs += d*d; }
    float rs = rsqrtf(vs*(1.f/64.f) + 1e-5f);
    mu_q[tid] = mu; rs_q[tid] = rs;

    s = 0.f;
    for (int h = 0; h < 64; ++h) s += Cs[tid][64+h];
    float mu2 = s * (1.f/64.f);
    vs = 0.f;
    for (int h = 0; h < 64; ++h) { float d = Cs[tid][64+h] - mu2; vs += d*d; }
    float rs2 = rsqrtf(vs*(1.f/64.f) + 1e-5f);
    mu_k[tid] = mu2; rs_k[tid] = rs2;

    int m = rowbase + tid;
    int tindex = m % T_;
    if (tindex >= 1) {            // non-prefix rows: alpha / sigma heads on LN'd q
      int bb = m / T_;
      int g = tindex - 1;
      float za = 0.f, z0 = 0.f, z1 = 0.f;
      for (int h = 0; h < 64; ++h) {
        float qv = (Cs[tid][h] - mu) * rs * qg[h] + qb[h];
        za += qv * walp[h];
        z0 += qv * wsig[2*h];
        z1 += qv * wsig[2*h+1];
      }
      za += balp[0]; z0 += bsig[0]; z1 += bsig[1];
      float al = fmaxf(za, 0.f) + log1pf(__expf(-fabsf(za)));   // softplus
      float sx = 1.f/(1.f + __expf(-z0));
      float sy = 1.f/(1.f + __expf(-z1));
      alo[bb*N_ + g] = al;
      sxo[bb*N_ + g] = 0.5f/(sx*sx);    // 1/(2*sx^2), pairs with dx^2 (col diff)
      syo[bb*N_ + g] = 0.5f/(sy*sy);
    }
  }
  __syncthreads();
  // coalesced-ish LN-apply + store of q,k,v
  for (int idx = tid; idx < 64*192; idx += 256) {
    int r = idx / 192, c = idx - (idx/192)*192;
    float val = Cs[r][c];
    size_t row = (size_t)rowbase + r;
    if (c < 64) {
      qo[row*64 + c] = (val - mu_q[r]) * rs_q[r] * qg[c] + qb[c];
    } else if (c < 128) {
      int h = c - 64;
      ko[row*64 + h] = (val - mu_k[r]) * rs_k[r] * kg[h] + kb[h];
    } else {
      vo[row*64 + (c-128)] = val;
    }
  }
}

// -------------------- Kernel 2: flash attention + Gaussian bias --------------------
// grid (37, 64): 16 q-rows per block; wave w owns q rows 4w..4w+3; lane = key (S) / dim (PV).
__global__ __launch_bounds__(256) void attn_kernel(
    const float* __restrict__ q, const float* __restrict__ k, const float* __restrict__ v,
    const float* __restrict__ ala, const float* __restrict__ sxa, const float* __restrict__ sya,
    float* __restrict__ out)
{
  __shared__ float4 q_s[16][17];     // q pre-scaled by 1/8, row-padded
  __shared__ float4 k_s[64][17];
  __shared__ float  v_s[64][65];
  __shared__ float4 p_s[4][64];      // per-wave P (4 rows packed per float4)
  __shared__ float par_al[16], par_sx[16], par_sy[16], par_gr[16], par_gc[16];
  __shared__ int   par_has[16];

  const int tid  = threadIdx.x;
  const int lane = tid & 63;
  const int w    = tid >> 6;
  const int b    = blockIdx.y;
  const int qt   = blockIdx.x;

  const float* qbase = q + (size_t)b * T_ * H_;
  const float* kbase = k + (size_t)b * T_ * H_;
  const float* vbase = v + (size_t)b * T_ * H_;

  {
    int r = tid >> 4, c4 = tid & 15;
    int row = qt*16 + r;
    int rowc = row < T_ ? row : T_ - 1;
    float4 val = *(const float4*)(qbase + (size_t)rowc*H_ + c4*4);
    val.x *= 0.125f; val.y *= 0.125f; val.z *= 0.125f; val.w *= 0.125f;
    q_s[r][c4] = val;
  }
  if (tid < 16) {
    int row = qt*16 + tid;
    float al=0.f, isx=0.f, isy=0.f, gr=0.f, gc=0.f; int has = 0;
    if (row >= 1 && row < T_) {
      int g = row - 1;
      al  = ala[b*N_ + g] * 0.125f;   // fold 1/sqrt(H) into alpha
      isx = sxa[b*N_ + g];
      isy = sya[b*N_ + g];
      gr  = (float)(g / GW_);
      gc  = (float)(g - (g/GW_)*GW_);
      has = 1;
    }
    par_al[tid]=al; par_sx[tid]=isx; par_sy[tid]=isy;
    par_gr[tid]=gr; par_gc[tid]=gc; par_has[tid]=has;
  }
  __syncthreads();

  const int r0 = w*4;
  float pal[4], psx[4], psy[4], pgr[4], pgc[4]; int phas[4];
  #pragma unroll
  for (int r = 0; r < 4; ++r) {
    pal[r]=par_al[r0+r]; psx[r]=par_sx[r0+r]; psy[r]=par_sy[r0+r];
    pgr[r]=par_gr[r0+r]; pgc[r]=par_gc[r0+r]; phas[r]=par_has[r0+r];
  }

  float mr[4], lr[4], o[4];
  #pragma unroll
  for (int r = 0; r < 4; ++r) { mr[r] = -INFINITY; lr[r] = 0.f; o[r] = 0.f; }

  const int NT = (T_ + 63) / 64;   // 10 key tiles
  for (int kt = 0; kt < NT; ++kt) {
    __syncthreads();
    #pragma unroll
    for (int i = 0; i < 4; ++i) {
      int s = tid + 256*i;         // 0..1023
      int r = s >> 4, c4 = s & 15;
      int key = kt*64 + r;
      int keyc = key < T_ ? key : T_ - 1;
      k_s[r][c4] = *(const float4*)(kbase + (size_t)keyc*H_ + c4*4);
      float4 vv  = *(const float4*)(vbase + (size_t)keyc*H_ + c4*4);
      v_s[r][c4*4+0]=vv.x; v_s[r][c4*4+1]=vv.y; v_s[r][c4*4+2]=vv.z; v_s[r][c4*4+3]=vv.w;
    }
    __syncthreads();

    // S = (q/8) . k for 4 rows x key=lane
    const int j = lane;
    float s0=0.f, s1=0.f, s2=0.f, s3=0.f;
    #pragma unroll 4
    for (int hq = 0; hq < 16; ++hq) {
      float4 kk4 = k_s[j][hq];
      float4 qa = q_s[r0+0][hq];
      float4 qb_ = q_s[r0+1][hq];
      float4 qc = q_s[r0+2][hq];
      float4 qd = q_s[r0+3][hq];
      s0 += qa.x*kk4.x + qa.y*kk4.y + qa.z*kk4.z + qa.w*kk4.w;
      s1 += qb_.x*kk4.x + qb_.y*kk4.y + qb_.z*kk4.z + qb_.w*kk4.w;
      s2 += qc.x*kk4.x + qc.y*kk4.y + qc.z*kk4.z + qc.w*kk4.w;
      s3 += qd.x*kk4.x + qd.y*kk4.y + qd.z*kk4.z + qd.w*kk4.w;
    }
    float sv[4] = {s0, s1, s2, s3};

    int key = kt*64 + j;
    bool kvalid = key < T_;
    if (kvalid && key >= 1) {
      int kg = key - 1;
      float kr = (float)(kg / GW_);
      float kc = (float)(kg - (kg/GW_)*GW_);
      #pragma unroll
      for (int r = 0; r < 4; ++r) {
        if (phas[r]) {
          float dx = pgc[r] - kc, dy = pgr[r] - kr;
          sv[r] += pal[r] * __expf(-(dx*dx)*psx[r] - (dy*dy)*psy[r]);
        }
      }
    }
    if (!kvalid) { sv[0]=-1e30f; sv[1]=-1e30f; sv[2]=-1e30f; sv[3]=-1e30f; }

    // online softmax per row (wave-wide reductions)
    float pv[4], sc[4];
    #pragma unroll
    for (int r = 0; r < 4; ++r) {
      float mx = sv[r];
      #pragma unroll
      for (int off = 32; off > 0; off >>= 1) mx = fmaxf(mx, __shfl_xor(mx, off, 64));
      float mnew = fmaxf(mr[r], mx);
      float p = __expf(sv[r] - mnew);
      float ls = p;
      #pragma unroll
      for (int off = 32; off > 0; off >>= 1) ls += __shfl_xor(ls, off, 64);
      sc[r] = __expf(mr[r] - mnew);
      lr[r] = lr[r]*sc[r] + ls;
      mr[r] = mnew;
      pv[r] = p;
    }
    p_s[w][j] = make_float4(pv[0], pv[1], pv[2], pv[3]);   // same-wave producer/consumer
    #pragma unroll
    for (int r = 0; r < 4; ++r) o[r] *= sc[r];

    // O += P @ V  (lane = output dim)
    const int d = lane;
    #pragma unroll 8
    for (int jj = 0; jj < 64; ++jj) {
      float4 p4 = p_s[w][jj];      // broadcast
      float vvv = v_s[jj][d];      // conflict-free
      o[0] += p4.x*vvv;
      o[1] += p4.y*vvv;
      o[2] += p4.z*vvv;
      o[3] += p4.w*vvv;
    }
  }

  #pragma unroll
  for (int r = 0; r < 4; ++r) {
    int row = qt*16 + r0 + r;
    if (row < T_) {
      out[((size_t)b*T_ + row)*H_ + lane] = o[r] / lr[r];
    }
  }
}

extern "C" void kernel_launch(void* const* d_in, const int* in_sizes, int n_in,
                              void* d_out, int out_size, void* d_ws, size_t ws_size,
                              hipStream_t stream) {
  const float* x      = (const float*)d_in[0];
  const float* wq     = (const float*)d_in[1];
  const float* wk     = (const float*)d_in[2];
  const float* wv     = (const float*)d_in[3];
  const float* qg     = (const float*)d_in[4];
  const float* qb     = (const float*)d_in[5];
  const float* kg     = (const float*)d_in[6];
  const float* kb     = (const float*)d_in[7];
  const float* wsig   = (const float*)d_in[8];
  const float* bsig   = (const float*)d_in[9];
  const float* walp   = (const float*)d_in[10];
  const float* balp   = (const float*)d_in[11];
  float* out = (float*)d_out;

  float* ws  = (float*)d_ws;
  const size_t nrow = (size_t)B_ * T_;        // 36928
  float* qo  = ws;
  float* ko  = qo + nrow*H_;
  float* vo  = ko + nrow*H_;
  float* alo = vo + nrow*H_;
  float* sxo = alo + (size_t)B_*N_;
  float* syo = sxo + (size_t)B_*N_;
  // total ws use: 3*nrow*64 + 3*B*576 floats ~= 28.9 MB

  hipLaunchKernelGGL(qkv_ln_kernel, dim3(577), dim3(256), 0, stream,
                     x, wq, wk, wv, qg, qb, kg, kb, wsig, bsig, walp, balp,
                     qo, ko, vo, alo, sxo, syo);
  hipLaunchKernelGGL(attn_kernel, dim3((T_ + 15)/16, B_), dim3(256), 0, stream,
                     qo, ko, vo, alo, sxo, syo, out);
}

// Round 3
// 449.411 us; speedup vs baseline: 1.3037x; 1.3037x over previous
//
#include <hip/hip_runtime.h>
#include <math.h>

#define B_ 64
#define T_ 577
#define E_ 768
#define H_ 64
#define N_ 576
#define GW_ 24

typedef float f32x4 __attribute__((ext_vector_type(4)));
typedef __bf16 bf16x8 __attribute__((ext_vector_type(8)));
typedef __bf16 bf16x4 __attribute__((ext_vector_type(4)));

__device__ inline void split_bf16(float f, __bf16& h, __bf16& l) {
  h = (__bf16)f;
  l = (__bf16)(f - (float)h);
}

// -------------------- Kernel 0: W -> split-bf16, chunked transposed layout --------------------
// Wsw[kc][n][kk] with kc=0..23 (K-chunks of 32), n=0..191 (q|k|v cols), kk=0..31.
__global__ __launch_bounds__(256) void prep_w_kernel(
    const float* __restrict__ wq, const float* __restrict__ wk, const float* __restrict__ wv,
    __bf16* __restrict__ wsw_hi, __bf16* __restrict__ wsw_lo)
{
  int idx = blockIdx.x * 256 + threadIdx.x;   // < 24*192*32 = 147456
  int kk = idx & 31;
  int n  = (idx >> 5) % 192;
  int kc = idx / (192 * 32);
  int k  = kc * 32 + kk;
  const float* src = (n < 64) ? wq : ((n < 128) ? wk : wv);
  int nn = n & 63;
  float f = src[(size_t)k * 64 + nn];
  __bf16 h, l;
  split_bf16(f, h, l);
  wsw_hi[idx] = h;
  wsw_lo[idx] = l;
}

// -------------------- Kernel 1: MFMA qkv + LN + alpha/sigma heads --------------------
// grid 577 blocks (64 rows each), 256 threads (4 waves).
// Wave w computes all 64 rows x cols [48w, 48w+48): 4 m-tiles x 3 n-tiles of 16x16.
__global__ __launch_bounds__(256) void qkv_ln_kernel(
    const float* __restrict__ x,
    const __bf16* __restrict__ wsw_hi, const __bf16* __restrict__ wsw_lo,
    const float* __restrict__ qg, const float* __restrict__ qb,
    const float* __restrict__ kg, const float* __restrict__ kb,
    const float* __restrict__ wsig, const float* __restrict__ bsig,
    const float* __restrict__ walp, const float* __restrict__ balp,
    float* __restrict__ qo, float* __restrict__ ko, float* __restrict__ vo,
    float* __restrict__ alo, float* __restrict__ sxo, float* __restrict__ syo)
{
  // Stage buffers (32 KB) aliased with C tile (49.4 KB) + stats.
  __shared__ __align__(16) float smem[64*193 + 256];
  __bf16 (*A_hi)[32] = (__bf16 (*)[32])smem;                  // 64x32 bf16 = 4KB (1024 floats)
  __bf16 (*A_lo)[32] = (__bf16 (*)[32])(smem + 1024);
  __bf16 (*B_hi)[32] = (__bf16 (*)[32])(smem + 2048);         // 192x32 bf16 = 12KB (3072 floats)
  __bf16 (*B_lo)[32] = (__bf16 (*)[32])(smem + 2048 + 3072);
  float (*Cs)[193]   = (float (*)[193])smem;
  float* mu_q = smem + 64*193;
  float* rs_q = mu_q + 64;
  float* mu_k = rs_q + 64;
  float* rs_k = mu_k + 64;

  const int tid  = threadIdx.x;
  const int lane = tid & 63;
  const int w    = tid >> 6;
  const int rowbase = blockIdx.x << 6;

  f32x4 acc[4][3];
  #pragma unroll
  for (int mt = 0; mt < 4; ++mt)
    #pragma unroll
    for (int nt = 0; nt < 3; ++nt)
      acc[mt][nt] = (f32x4){0.f, 0.f, 0.f, 0.f};

  const int m     = lane & 15;
  const int kfrag = (lane >> 4) * 8;

  #pragma unroll 1
  for (int kc = 0; kc < 24; ++kc) {
    __syncthreads();
    // stage x tile 64x32 fp32 -> split bf16 (2 float4 per thread)
    #pragma unroll
    for (int i = 0; i < 2; ++i) {
      int s = tid + 256*i;               // 0..511
      int row = s >> 3, k4 = (s & 7) * 4;
      float4 xv = *(const float4*)(x + (size_t)(rowbase + row)*E_ + kc*32 + k4);
      __bf16 h0,l0,h1,l1,h2,l2,h3,l3;
      split_bf16(xv.x, h0, l0); split_bf16(xv.y, h1, l1);
      split_bf16(xv.z, h2, l2); split_bf16(xv.w, h3, l3);
      *(bf16x4*)&A_hi[row][k4] = (bf16x4){h0,h1,h2,h3};
      *(bf16x4*)&A_lo[row][k4] = (bf16x4){l0,l1,l2,l3};
    }
    // stage W chunk (pre-swizzled [n][k]) : 6144 bf16 each of hi/lo = 768 groups of 8
    #pragma unroll
    for (int i = 0; i < 3; ++i) {
      int e = tid + 256*i;               // 0..767
      bf16x8 hv = *(const bf16x8*)(wsw_hi + (size_t)kc*6144 + e*8);
      bf16x8 lv = *(const bf16x8*)(wsw_lo + (size_t)kc*6144 + e*8);
      *(bf16x8*)(((__bf16*)B_hi) + e*8) = hv;
      *(bf16x8*)(((__bf16*)B_lo) + e*8) = lv;
    }
    __syncthreads();

    bf16x8 bh[3], bl[3];
    #pragma unroll
    for (int nt = 0; nt < 3; ++nt) {
      int n = w*48 + nt*16 + m;
      bh[nt] = *(const bf16x8*)&B_hi[n][kfrag];
      bl[nt] = *(const bf16x8*)&B_lo[n][kfrag];
    }
    #pragma unroll
    for (int mt = 0; mt < 4; ++mt) {
      bf16x8 ah = *(const bf16x8*)&A_hi[mt*16 + m][kfrag];
      bf16x8 al = *(const bf16x8*)&A_lo[mt*16 + m][kfrag];
      #pragma unroll
      for (int nt = 0; nt < 3; ++nt) {
        acc[mt][nt] = __builtin_amdgcn_mfma_f32_16x16x32_bf16(ah, bh[nt], acc[mt][nt], 0, 0, 0);
        acc[mt][nt] = __builtin_amdgcn_mfma_f32_16x16x32_bf16(al, bh[nt], acc[mt][nt], 0, 0, 0);
        acc[mt][nt] = __builtin_amdgcn_mfma_f32_16x16x32_bf16(ah, bl[nt], acc[mt][nt], 0, 0, 0);
      }
    }
  }
  __syncthreads();   // all LDS frag reads done before aliasing as C tile

  // C layout: col = lane&15, row = (lane>>4)*4 + reg
  #pragma unroll
  for (int mt = 0; mt < 4; ++mt)
    #pragma unroll
    for (int nt = 0; nt < 3; ++nt) {
      int row = mt*16 + (lane >> 4)*4;
      int col = w*48 + nt*16 + (lane & 15);
      Cs[row + 0][col] = acc[mt][nt].x;
      Cs[row + 1][col] = acc[mt][nt].y;
      Cs[row + 2][col] = acc[mt][nt].z;
      Cs[row + 3][col] = acc[mt][nt].w;
    }
  __syncthreads();

  // per-row stats + heads (one thread per row; cols 0..63=q, 64..127=k, 128..191=v)
  if (tid < 64) {
    float s = 0.f;
    for (int h = 0; h < 64; ++h) s += Cs[tid][h];
    float mu = s * (1.f/64.f);
    float vs = 0.f;
    for (int h = 0; h < 64; ++h) { float d = Cs[tid][h] - mu; vs += d*d; }
    float rs = rsqrtf(vs*(1.f/64.f) + 1e-5f);
    mu_q[tid] = mu; rs_q[tid] = rs;

    s = 0.f;
    for (int h = 0; h < 64; ++h) s += Cs[tid][64+h];
    float mu2 = s * (1.f/64.f);
    vs = 0.f;
    for (int h = 0; h < 64; ++h) { float d = Cs[tid][64+h] - mu2; vs += d*d; }
    float rs2 = rsqrtf(vs*(1.f/64.f) + 1e-5f);
    mu_k[tid] = mu2; rs_k[tid] = rs2;

    int mrow = rowbase + tid;
    int tindex = mrow % T_;
    if (tindex >= 1) {            // non-prefix rows: alpha / sigma heads on LN'd q
      int bb = mrow / T_;
      int g = tindex - 1;
      float za = 0.f, z0 = 0.f, z1 = 0.f;
      for (int h = 0; h < 64; ++h) {
        float qv = (Cs[tid][h] - mu) * rs * qg[h] + qb[h];
        za += qv * walp[h];
        z0 += qv * wsig[2*h];
        z1 += qv * wsig[2*h+1];
      }
      za += balp[0]; z0 += bsig[0]; z1 += bsig[1];
      float al = fmaxf(za, 0.f) + log1pf(__expf(-fabsf(za)));   // softplus
      float sx = 1.f/(1.f + __expf(-z0));
      float sy = 1.f/(1.f + __expf(-z1));
      alo[bb*N_ + g] = al;
      sxo[bb*N_ + g] = 0.5f/(sx*sx);    // 1/(2*sx^2), pairs with dx^2 (col diff)
      syo[bb*N_ + g] = 0.5f/(sy*sy);
    }
  }
  __syncthreads();
  // LN-apply + store of q,k,v
  for (int idx = tid; idx < 64*192; idx += 256) {
    int r = idx / 192, c = idx - (idx/192)*192;
    float val = Cs[r][c];
    size_t row = (size_t)rowbase + r;
    if (c < 64) {
      qo[row*64 + c] = (val - mu_q[r]) * rs_q[r] * qg[c] + qb[c];
    } else if (c < 128) {
      int h = c - 64;
      ko[row*64 + h] = (val - mu_k[r]) * rs_k[r] * kg[h] + kb[h];
    } else {
      vo[row*64 + (c-128)] = val;
    }
  }
}

// -------------------- Kernel 2: flash attention + Gaussian bias --------------------
// grid (37, 64): 16 q-rows per block; wave w owns q rows 4w..4w+3; lane = key (S) / dim (PV).
__global__ __launch_bounds__(256) void attn_kernel(
    const float* __restrict__ q, const float* __restrict__ k, const float* __restrict__ v,
    const float* __restrict__ ala, const float* __restrict__ sxa, const float* __restrict__ sya,
    float* __restrict__ out)
{
  __shared__ float4 q_s[16][17];     // q pre-scaled by 1/8, row-padded
  __shared__ float4 k_s[64][17];
  __shared__ float  v_s[64][65];
  __shared__ float4 p_s[4][64];      // per-wave P (4 rows packed per float4)
  __shared__ float par_al[16], par_sx[16], par_sy[16], par_gr[16], par_gc[16];
  __shared__ int   par_has[16];

  const int tid  = threadIdx.x;
  const int lane = tid & 63;
  const int w    = tid >> 6;
  const int b    = blockIdx.y;
  const int qt   = blockIdx.x;

  const float* qbase = q + (size_t)b * T_ * H_;
  const float* kbase = k + (size_t)b * T_ * H_;
  const float* vbase = v + (size_t)b * T_ * H_;

  {
    int r = tid >> 4, c4 = tid & 15;
    int row = qt*16 + r;
    int rowc = row < T_ ? row : T_ - 1;
    float4 val = *(const float4*)(qbase + (size_t)rowc*H_ + c4*4);
    val.x *= 0.125f; val.y *= 0.125f; val.z *= 0.125f; val.w *= 0.125f;
    q_s[r][c4] = val;
  }
  if (tid < 16) {
    int row = qt*16 + tid;
    float al=0.f, isx=0.f, isy=0.f, gr=0.f, gc=0.f; int has = 0;
    if (row >= 1 && row < T_) {
      int g = row - 1;
      al  = ala[b*N_ + g] * 0.125f;   // fold 1/sqrt(H) into alpha
      isx = sxa[b*N_ + g];
      isy = sya[b*N_ + g];
      gr  = (float)(g / GW_);
      gc  = (float)(g - (g/GW_)*GW_);
      has = 1;
    }
    par_al[tid]=al; par_sx[tid]=isx; par_sy[tid]=isy;
    par_gr[tid]=gr; par_gc[tid]=gc; par_has[tid]=has;
  }
  __syncthreads();

  const int r0 = w*4;
  float pal[4], psx[4], psy[4], pgr[4], pgc[4]; int phas[4];
  #pragma unroll
  for (int r = 0; r < 4; ++r) {
    pal[r]=par_al[r0+r]; psx[r]=par_sx[r0+r]; psy[r]=par_sy[r0+r];
    pgr[r]=par_gr[r0+r]; pgc[r]=par_gc[r0+r]; phas[r]=par_has[r0+r];
  }

  float mr[4], lr[4], o[4];
  #pragma unroll
  for (int r = 0; r < 4; ++r) { mr[r] = -INFINITY; lr[r] = 0.f; o[r] = 0.f; }

  const int NT = (T_ + 63) / 64;   // 10 key tiles
  for (int kt = 0; kt < NT; ++kt) {
    __syncthreads();
    #pragma unroll
    for (int i = 0; i < 4; ++i) {
      int s = tid + 256*i;         // 0..1023
      int r = s >> 4, c4 = s & 15;
      int key = kt*64 + r;
      int keyc = key < T_ ? key : T_ - 1;
      k_s[r][c4] = *(const float4*)(kbase + (size_t)keyc*H_ + c4*4);
      float4 vv  = *(const float4*)(vbase + (size_t)keyc*H_ + c4*4);
      v_s[r][c4*4+0]=vv.x; v_s[r][c4*4+1]=vv.y; v_s[r][c4*4+2]=vv.z; v_s[r][c4*4+3]=vv.w;
    }
    __syncthreads();

    // S = (q/8) . k for 4 rows x key=lane
    const int j = lane;
    float s0=0.f, s1=0.f, s2=0.f, s3=0.f;
    #pragma unroll 4
    for (int hq = 0; hq < 16; ++hq) {
      float4 kk4 = k_s[j][hq];
      float4 qa = q_s[r0+0][hq];
      float4 qb_ = q_s[r0+1][hq];
      float4 qc = q_s[r0+2][hq];
      float4 qd = q_s[r0+3][hq];
      s0 += qa.x*kk4.x + qa.y*kk4.y + qa.z*kk4.z + qa.w*kk4.w;
      s1 += qb_.x*kk4.x + qb_.y*kk4.y + qb_.z*kk4.z + qb_.w*kk4.w;
      s2 += qc.x*kk4.x + qc.y*kk4.y + qc.z*kk4.z + qc.w*kk4.w;
      s3 += qd.x*kk4.x + qd.y*kk4.y + qd.z*kk4.z + qd.w*kk4.w;
    }
    float sv[4] = {s0, s1, s2, s3};

    int key = kt*64 + j;
    bool kvalid = key < T_;
    if (kvalid && key >= 1) {
      int kg = key - 1;
      float kr = (float)(kg / GW_);
      float kc = (float)(kg - (kg/GW_)*GW_);
      #pragma unroll
      for (int r = 0; r < 4; ++r) {
        if (phas[r]) {
          float dx = pgc[r] - kc, dy = pgr[r] - kr;
          sv[r] += pal[r] * __expf(-(dx*dx)*psx[r] - (dy*dy)*psy[r]);
        }
      }
    }
    if (!kvalid) { sv[0]=-1e30f; sv[1]=-1e30f; sv[2]=-1e30f; sv[3]=-1e30f; }

    // online softmax per row (wave-wide reductions)
    float pv[4], sc[4];
    #pragma unroll
    for (int r = 0; r < 4; ++r) {
      float mx = sv[r];
      #pragma unroll
      for (int off = 32; off > 0; off >>= 1) mx = fmaxf(mx, __shfl_xor(mx, off, 64));
      float mnew = fmaxf(mr[r], mx);
      float p = __expf(sv[r] - mnew);
      float ls = p;
      #pragma unroll
      for (int off = 32; off > 0; off >>= 1) ls += __shfl_xor(ls, off, 64);
      sc[r] = __expf(mr[r] - mnew);
      lr[r] = lr[r]*sc[r] + ls;
      mr[r] = mnew;
      pv[r] = p;
    }
    p_s[w][j] = make_float4(pv[0], pv[1], pv[2], pv[3]);   // same-wave producer/consumer
    #pragma unroll
    for (int r = 0; r < 4; ++r) o[r] *= sc[r];

    // O += P @ V  (lane = output dim)
    const int d = lane;
    #pragma unroll 8
    for (int jj = 0; jj < 64; ++jj) {
      float4 p4 = p_s[w][jj];      // broadcast
      float vvv = v_s[jj][d];      // conflict-free
      o[0] += p4.x*vvv;
      o[1] += p4.y*vvv;
      o[2] += p4.z*vvv;
      o[3] += p4.w*vvv;
    }
  }

  #pragma unroll
  for (int r = 0; r < 4; ++r) {
    int row = qt*16 + r0 + r;
    if (row < T_) {
      out[((size_t)b*T_ + row)*H_ + lane] = o[r] / lr[r];
    }
  }
}

extern "C" void kernel_launch(void* const* d_in, const int* in_sizes, int n_in,
                              void* d_out, int out_size, void* d_ws, size_t ws_size,
                              hipStream_t stream) {
  const float* x      = (const float*)d_in[0];
  const float* wq     = (const float*)d_in[1];
  const float* wk     = (const float*)d_in[2];
  const float* wv     = (const float*)d_in[3];
  const float* qg     = (const float*)d_in[4];
  const float* qb     = (const float*)d_in[5];
  const float* kg     = (const float*)d_in[6];
  const float* kb     = (const float*)d_in[7];
  const float* wsig   = (const float*)d_in[8];
  const float* bsig   = (const float*)d_in[9];
  const float* walp   = (const float*)d_in[10];
  const float* balp   = (const float*)d_in[11];
  float* out = (float*)d_out;

  float* ws  = (float*)d_ws;
  const size_t nrow = (size_t)B_ * T_;        // 36928
  float* qo  = ws;
  float* ko  = qo + nrow*H_;
  float* vo  = ko + nrow*H_;
  float* alo = vo + nrow*H_;
  float* sxo = alo + (size_t)B_*N_;
  float* syo = sxo + (size_t)B_*N_;
  __bf16* wsw_hi = (__bf16*)(syo + (size_t)B_*N_);    // 147456 bf16
  __bf16* wsw_lo = wsw_hi + 24*192*32;
  // total ws use: ~29.4 MB

  hipLaunchKernelGGL(prep_w_kernel, dim3(576), dim3(256), 0, stream,
                     wq, wk, wv, wsw_hi, wsw_lo);
  hipLaunchKernelGGL(qkv_ln_kernel, dim3(577), dim3(256), 0, stream,
                     x, wsw_hi, wsw_lo, qg, qb, kg, kb, wsig, bsig, walp, balp,
                     qo, ko, vo, alo, sxo, syo);
  hipLaunchKernelGGL(attn_kernel, dim3((T_ + 15)/16, B_), dim3(256), 0, stream,
                     qo, ko, vo, alo, sxo, syo, out);
}

// Round 4
// 297.914 us; speedup vs baseline: 1.9667x; 1.5085x over previous
//
#include <hip/hip_runtime.h>
#include <math.h>

#define B_ 64
#define T_ 577
#define E_ 768
#define H_ 64
#define N_ 576
#define GW_ 24

typedef float f32x4 __attribute__((ext_vector_type(4)));
typedef __bf16 bf16x8 __attribute__((ext_vector_type(8)));
typedef __bf16 bf16x4 __attribute__((ext_vector_type(4)));

__device__ inline void split_bf16(float f, __bf16& h, __bf16& l) {
  h = (__bf16)f;
  l = (__bf16)(f - (float)h);
}

// -------------------- Kernel 0: W -> split-bf16, chunked transposed layout --------------------
__global__ __launch_bounds__(256) void prep_w_kernel(
    const float* __restrict__ wq, const float* __restrict__ wk, const float* __restrict__ wv,
    __bf16* __restrict__ wsw_hi, __bf16* __restrict__ wsw_lo)
{
  int idx = blockIdx.x * 256 + threadIdx.x;   // < 24*192*32 = 147456
  int kk = idx & 31;
  int n  = (idx >> 5) % 192;
  int kc = idx / (192 * 32);
  int k  = kc * 32 + kk;
  const float* src = (n < 64) ? wq : ((n < 128) ? wk : wv);
  int nn = n & 63;
  float f = src[(size_t)k * 64 + nn];
  __bf16 h, l;
  split_bf16(f, h, l);
  wsw_hi[idx] = h;
  wsw_lo[idx] = l;
}

// -------------------- Kernel 1: MFMA qkv + LN + alpha/sigma heads --------------------
__global__ __launch_bounds__(256) void qkv_ln_kernel(
    const float* __restrict__ x,
    const __bf16* __restrict__ wsw_hi, const __bf16* __restrict__ wsw_lo,
    const float* __restrict__ qg, const float* __restrict__ qb,
    const float* __restrict__ kg, const float* __restrict__ kb,
    const float* __restrict__ wsig, const float* __restrict__ bsig,
    const float* __restrict__ walp, const float* __restrict__ balp,
    float* __restrict__ qo, float* __restrict__ ko, float* __restrict__ vo,
    float* __restrict__ alo, float* __restrict__ sxo, float* __restrict__ syo)
{
  __shared__ __align__(16) float smem[64*193 + 256];
  __bf16 (*A_hi)[32] = (__bf16 (*)[32])smem;
  __bf16 (*A_lo)[32] = (__bf16 (*)[32])(smem + 1024);
  __bf16 (*B_hi)[32] = (__bf16 (*)[32])(smem + 2048);
  __bf16 (*B_lo)[32] = (__bf16 (*)[32])(smem + 2048 + 3072);
  float (*Cs)[193]   = (float (*)[193])smem;
  float* mu_q = smem + 64*193;
  float* rs_q = mu_q + 64;
  float* mu_k = rs_q + 64;
  float* rs_k = mu_k + 64;

  const int tid  = threadIdx.x;
  const int lane = tid & 63;
  const int w    = tid >> 6;
  const int rowbase = blockIdx.x << 6;

  f32x4 acc[4][3];
  #pragma unroll
  for (int mt = 0; mt < 4; ++mt)
    #pragma unroll
    for (int nt = 0; nt < 3; ++nt)
      acc[mt][nt] = (f32x4){0.f, 0.f, 0.f, 0.f};

  const int m     = lane & 15;
  const int kfrag = (lane >> 4) * 8;

  #pragma unroll 1
  for (int kc = 0; kc < 24; ++kc) {
    __syncthreads();
    #pragma unroll
    for (int i = 0; i < 2; ++i) {
      int s = tid + 256*i;
      int row = s >> 3, k4 = (s & 7) * 4;
      float4 xv = *(const float4*)(x + (size_t)(rowbase + row)*E_ + kc*32 + k4);
      __bf16 h0,l0,h1,l1,h2,l2,h3,l3;
      split_bf16(xv.x, h0, l0); split_bf16(xv.y, h1, l1);
      split_bf16(xv.z, h2, l2); split_bf16(xv.w, h3, l3);
      *(bf16x4*)&A_hi[row][k4] = (bf16x4){h0,h1,h2,h3};
      *(bf16x4*)&A_lo[row][k4] = (bf16x4){l0,l1,l2,l3};
    }
    #pragma unroll
    for (int i = 0; i < 3; ++i) {
      int e = tid + 256*i;
      bf16x8 hv = *(const bf16x8*)(wsw_hi + (size_t)kc*6144 + e*8);
      bf16x8 lv = *(const bf16x8*)(wsw_lo + (size_t)kc*6144 + e*8);
      *(bf16x8*)(((__bf16*)B_hi) + e*8) = hv;
      *(bf16x8*)(((__bf16*)B_lo) + e*8) = lv;
    }
    __syncthreads();

    bf16x8 bh[3], bl[3];
    #pragma unroll
    for (int nt = 0; nt < 3; ++nt) {
      int n = w*48 + nt*16 + m;
      bh[nt] = *(const bf16x8*)&B_hi[n][kfrag];
      bl[nt] = *(const bf16x8*)&B_lo[n][kfrag];
    }
    #pragma unroll
    for (int mt = 0; mt < 4; ++mt) {
      bf16x8 ah = *(const bf16x8*)&A_hi[mt*16 + m][kfrag];
      bf16x8 al = *(const bf16x8*)&A_lo[mt*16 + m][kfrag];
      #pragma unroll
      for (int nt = 0; nt < 3; ++nt) {
        acc[mt][nt] = __builtin_amdgcn_mfma_f32_16x16x32_bf16(ah, bh[nt], acc[mt][nt], 0, 0, 0);
        acc[mt][nt] = __builtin_amdgcn_mfma_f32_16x16x32_bf16(al, bh[nt], acc[mt][nt], 0, 0, 0);
        acc[mt][nt] = __builtin_amdgcn_mfma_f32_16x16x32_bf16(ah, bl[nt], acc[mt][nt], 0, 0, 0);
      }
    }
  }
  __syncthreads();

  #pragma unroll
  for (int mt = 0; mt < 4; ++mt)
    #pragma unroll
    for (int nt = 0; nt < 3; ++nt) {
      int row = mt*16 + (lane >> 4)*4;
      int col = w*48 + nt*16 + (lane & 15);
      Cs[row + 0][col] = acc[mt][nt].x;
      Cs[row + 1][col] = acc[mt][nt].y;
      Cs[row + 2][col] = acc[mt][nt].z;
      Cs[row + 3][col] = acc[mt][nt].w;
    }
  __syncthreads();

  if (tid < 64) {
    float s = 0.f;
    for (int h = 0; h < 64; ++h) s += Cs[tid][h];
    float mu = s * (1.f/64.f);
    float vs = 0.f;
    for (int h = 0; h < 64; ++h) { float d = Cs[tid][h] - mu; vs += d*d; }
    float rs = rsqrtf(vs*(1.f/64.f) + 1e-5f);
    mu_q[tid] = mu; rs_q[tid] = rs;

    s = 0.f;
    for (int h = 0; h < 64; ++h) s += Cs[tid][64+h];
    float mu2 = s * (1.f/64.f);
    vs = 0.f;
    for (int h = 0; h < 64; ++h) { float d = Cs[tid][64+h] - mu2; vs += d*d; }
    float rs2 = rsqrtf(vs*(1.f/64.f) + 1e-5f);
    mu_k[tid] = mu2; rs_k[tid] = rs2;

    int mrow = rowbase + tid;
    int tindex = mrow % T_;
    if (tindex >= 1) {
      int bb = mrow / T_;
      int g = tindex - 1;
      float za = 0.f, z0 = 0.f, z1 = 0.f;
      for (int h = 0; h < 64; ++h) {
        float qv = (Cs[tid][h] - mu) * rs * qg[h] + qb[h];
        za += qv * walp[h];
        z0 += qv * wsig[2*h];
        z1 += qv * wsig[2*h+1];
      }
      za += balp[0]; z0 += bsig[0]; z1 += bsig[1];
      float al = fmaxf(za, 0.f) + log1pf(__expf(-fabsf(za)));
      float sx = 1.f/(1.f + __expf(-z0));
      float sy = 1.f/(1.f + __expf(-z1));
      alo[bb*N_ + g] = al;
      sxo[bb*N_ + g] = 0.5f/(sx*sx);
      syo[bb*N_ + g] = 0.5f/(sy*sy);
    }
  }
  __syncthreads();
  for (int idx = tid; idx < 64*192; idx += 256) {
    int r = idx / 192, c = idx - (idx/192)*192;
    float val = Cs[r][c];
    size_t row = (size_t)rowbase + r;
    if (c < 64) {
      qo[row*64 + c] = (val - mu_q[r]) * rs_q[r] * qg[c] + qb[c];
    } else if (c < 128) {
      int h = c - 64;
      ko[row*64 + h] = (val - mu_k[r]) * rs_k[r] * kg[h] + kb[h];
    } else {
      vo[row*64 + (c-128)] = val;
    }
  }
}

// -------------------- Kernel 2: MFMA flash attention + Gaussian bias --------------------
// grid (10, 64): 64 q-rows per block, 4 waves; wave w owns the 16-row band [16w,16w+16).
// All LDS tiles padded to 72 bf16/row -> conflict-free ds_read_b128 fragments.
__global__ __launch_bounds__(256) void attn_kernel(
    const float* __restrict__ q, const float* __restrict__ k, const float* __restrict__ v,
    const float* __restrict__ ala, const float* __restrict__ sxa, const float* __restrict__ sya,
    float* __restrict__ out)
{
  __shared__ __align__(16) __bf16 sm[8*4608];   // 8 regions of 64x72
  __shared__ float prm_al[64], prm_sx[64], prm_sy[64], prm_gr[64], prm_gc[64];
  __shared__ int   prm_has[64];

  __bf16* QH = sm;            __bf16* QL = sm + 4608;
  __bf16* KH = sm + 2*4608;   __bf16* KL = sm + 3*4608;
  __bf16* VH = sm + 4*4608;   __bf16* VL = sm + 5*4608;   // V^T: [dim][key]
  __bf16* PH = sm + 6*4608;   __bf16* PL = sm + 7*4608;   // per-wave 16-row bands

  const int tid  = threadIdx.x;
  const int lane = tid & 63;
  const int w    = tid >> 6;
  const int quad = lane >> 4;
  const int mrow = lane & 15;
  const int b    = blockIdx.y;
  const int qt   = blockIdx.x;

  const float* qbase = q + (size_t)b * T_ * H_;
  const float* kbase = k + (size_t)b * T_ * H_;
  const float* vbase = v + (size_t)b * T_ * H_;

  // per-row params (row within this 64-row q tile)
  if (tid < 64) {
    int row = qt*64 + tid;
    float al=0.f, isx=0.f, isy=0.f, gr=0.f, gc=0.f; int has = 0;
    if (row >= 1 && row < T_) {
      int g = row - 1;
      al  = ala[b*N_ + g] * 0.125f;     // fold 1/sqrt(H)
      isx = sxa[b*N_ + g];
      isy = sya[b*N_ + g];
      gr  = (float)(g / GW_);
      gc  = (float)(g - (g/GW_)*GW_);
      has = 1;
    }
    prm_al[tid]=al; prm_sx[tid]=isx; prm_sy[tid]=isy;
    prm_gr[tid]=gr; prm_gc[tid]=gc; prm_has[tid]=has;
  }
  // stage Q (scaled by 1/8, split hi/lo)
  #pragma unroll
  for (int i = 0; i < 4; ++i) {
    int s = tid + 256*i;                 // 0..1023
    int r = s >> 4, c4 = (s & 15)*4;
    int row = qt*64 + r;
    int rowc = row < T_ ? row : T_ - 1;
    float4 v4 = *(const float4*)(qbase + (size_t)rowc*H_ + c4);
    v4.x *= 0.125f; v4.y *= 0.125f; v4.z *= 0.125f; v4.w *= 0.125f;
    __bf16 h0,l0,h1,l1,h2,l2,h3,l3;
    split_bf16(v4.x,h0,l0); split_bf16(v4.y,h1,l1);
    split_bf16(v4.z,h2,l2); split_bf16(v4.w,h3,l3);
    *(bf16x4*)&QH[r*72 + c4] = (bf16x4){h0,h1,h2,h3};
    *(bf16x4*)&QL[r*72 + c4] = (bf16x4){l0,l1,l2,l3};
  }
  __syncthreads();

  // per-lane row params (rows w*16 + quad*4 + reg)
  float p_al[4], p_sx[4], p_sy[4], p_gr[4], p_gc[4]; int p_has[4];
  #pragma unroll
  for (int reg = 0; reg < 4; ++reg) {
    int rr = w*16 + quad*4 + reg;
    p_al[reg]=prm_al[rr]; p_sx[reg]=prm_sx[rr]; p_sy[reg]=prm_sy[rr];
    p_gr[reg]=prm_gr[rr]; p_gc[reg]=prm_gc[rr]; p_has[reg]=prm_has[rr];
  }

  float mo[4], lsum[4], O_[4][4];
  #pragma unroll
  for (int reg = 0; reg < 4; ++reg) { mo[reg] = -INFINITY; lsum[reg] = 0.f; }
  #pragma unroll
  for (int nt = 0; nt < 4; ++nt)
    #pragma unroll
    for (int reg = 0; reg < 4; ++reg) O_[nt][reg] = 0.f;

  #pragma unroll 1
  for (int kt = 0; kt < 10; ++kt) {
    __syncthreads();
    // ---- stage K [key][72] ----
    #pragma unroll
    for (int i = 0; i < 4; ++i) {
      int s = tid + 256*i;
      int key = s >> 4, c4 = (s & 15)*4;
      int kgl = kt*64 + key;
      int kcl = kgl < T_ ? kgl : T_ - 1;
      float4 kv = *(const float4*)(kbase + (size_t)kcl*H_ + c4);
      __bf16 h0,l0,h1,l1,h2,l2,h3,l3;
      split_bf16(kv.x,h0,l0); split_bf16(kv.y,h1,l1);
      split_bf16(kv.z,h2,l2); split_bf16(kv.w,h3,l3);
      *(bf16x4*)&KH[key*72 + c4] = (bf16x4){h0,h1,h2,h3};
      *(bf16x4*)&KL[key*72 + c4] = (bf16x4){l0,l1,l2,l3};
    }
    // ---- stage V^T [dim][72] (dword loads, packed b64 writes) ----
    {
      int d0 = tid & 15, k0 = (tid >> 4) * 4;
      #pragma unroll
      for (int di = 0; di < 3 + 1; ++di) {
        int dim = d0 + 16*di;
        float vv[4];
        #pragma unroll
        for (int ki = 0; ki < 4; ++ki) {
          int kgl = kt*64 + k0 + ki;
          int kcl = kgl < T_ ? kgl : T_ - 1;
          vv[ki] = vbase[(size_t)kcl*H_ + dim];
        }
        __bf16 h0,l0,h1,l1,h2,l2,h3,l3;
        split_bf16(vv[0],h0,l0); split_bf16(vv[1],h1,l1);
        split_bf16(vv[2],h2,l2); split_bf16(vv[3],h3,l3);
        *(bf16x4*)&VH[dim*72 + k0] = (bf16x4){h0,h1,h2,h3};
        *(bf16x4*)&VL[dim*72 + k0] = (bf16x4){l0,l1,l2,l3};
      }
    }
    __syncthreads();

    // ---- S = (Q/8)·K^T : 4 n-tiles of 16x16, split 3-MFMA ----
    float S_[4][4];
    {
      f32x4 sac[4];
      #pragma unroll
      for (int nt = 0; nt < 4; ++nt) sac[nt] = (f32x4){0.f,0.f,0.f,0.f};
      #pragma unroll
      for (int ks = 0; ks < 2; ++ks) {
        int ko_ = ks*32 + quad*8;
        bf16x8 qh = *(const bf16x8*)&QH[(w*16 + mrow)*72 + ko_];
        bf16x8 ql = *(const bf16x8*)&QL[(w*16 + mrow)*72 + ko_];
        #pragma unroll
        for (int nt = 0; nt < 4; ++nt) {
          bf16x8 kh = *(const bf16x8*)&KH[(nt*16 + mrow)*72 + ko_];
          bf16x8 kl = *(const bf16x8*)&KL[(nt*16 + mrow)*72 + ko_];
          sac[nt] = __builtin_amdgcn_mfma_f32_16x16x32_bf16(qh, kh, sac[nt], 0, 0, 0);
          sac[nt] = __builtin_amdgcn_mfma_f32_16x16x32_bf16(ql, kh, sac[nt], 0, 0, 0);
          sac[nt] = __builtin_amdgcn_mfma_f32_16x16x32_bf16(qh, kl, sac[nt], 0, 0, 0);
        }
      }
      #pragma unroll
      for (int nt = 0; nt < 4; ++nt) {
        S_[nt][0] = sac[nt].x; S_[nt][1] = sac[nt].y;
        S_[nt][2] = sac[nt].z; S_[nt][3] = sac[nt].w;
      }
    }

    // ---- Gaussian bias + key masking (C layout: row=quad*4+reg, col=nt*16+mrow) ----
    #pragma unroll
    for (int nt = 0; nt < 4; ++nt) {
      int keyg = kt*64 + nt*16 + mrow;
      bool kval = keyg < T_;
      bool khas = (keyg >= 1) && kval;
      float kgf = (float)(keyg - 1);
      float krf = floorf(kgf * (1.0f/24.0f));
      float kcf = kgf - 24.f*krf;
      #pragma unroll
      for (int reg = 0; reg < 4; ++reg) {
        float sval = S_[nt][reg];
        float dx = p_gc[reg] - kcf, dy = p_gr[reg] - krf;
        float bias = p_al[reg] * __expf(-(dx*dx*p_sx[reg] + dy*dy*p_sy[reg]));
        sval += (khas && p_has[reg]) ? bias : 0.f;
        S_[nt][reg] = kval ? sval : -1e30f;
      }
    }

    // ---- online softmax (16-lane reductions within quad groups) ----
    float mt_[4], lt_[4], sc_[4], mn_[4];
    #pragma unroll
    for (int reg = 0; reg < 4; ++reg) {
      float mx = fmaxf(fmaxf(S_[0][reg], S_[1][reg]), fmaxf(S_[2][reg], S_[3][reg]));
      mx = fmaxf(mx, __shfl_xor(mx, 1, 64));
      mx = fmaxf(mx, __shfl_xor(mx, 2, 64));
      mx = fmaxf(mx, __shfl_xor(mx, 4, 64));
      mx = fmaxf(mx, __shfl_xor(mx, 8, 64));
      mt_[reg] = mx;
      mn_[reg] = fmaxf(mo[reg], mx);
      lt_[reg] = 0.f;
    }
    #pragma unroll
    for (int nt = 0; nt < 4; ++nt)
      #pragma unroll
      for (int reg = 0; reg < 4; ++reg) {
        float p = __expf(S_[nt][reg] - mn_[reg]);
        S_[nt][reg] = p;
        lt_[reg] += p;
      }
    #pragma unroll
    for (int reg = 0; reg < 4; ++reg) {
      float ls = lt_[reg];
      ls += __shfl_xor(ls, 1, 64);
      ls += __shfl_xor(ls, 2, 64);
      ls += __shfl_xor(ls, 4, 64);
      ls += __shfl_xor(ls, 8, 64);
      sc_[reg] = __expf(mo[reg] - mn_[reg]);
      lsum[reg] = lsum[reg]*sc_[reg] + ls;
      mo[reg] = mn_[reg];
    }
    #pragma unroll
    for (int nt = 0; nt < 4; ++nt)
      #pragma unroll
      for (int reg = 0; reg < 4; ++reg) O_[nt][reg] *= sc_[reg];

    // ---- pack P (split hi/lo) into per-wave LDS band; same-wave RAW -> no barrier ----
    #pragma unroll
    for (int nt = 0; nt < 4; ++nt)
      #pragma unroll
      for (int reg = 0; reg < 4; ++reg) {
        float p = S_[nt][reg];
        __bf16 ph, pl;
        split_bf16(p, ph, pl);
        int addr = (w*16 + quad*4 + reg)*72 + nt*16 + mrow;
        PH[addr] = ph;
        PL[addr] = pl;
      }

    // ---- O += P·V (A=P from LDS, B=V^T tiles, split 3-MFMA) ----
    #pragma unroll
    for (int nt = 0; nt < 4; ++nt) {
      f32x4 c = (f32x4){O_[nt][0], O_[nt][1], O_[nt][2], O_[nt][3]};
      #pragma unroll
      for (int ks = 0; ks < 2; ++ks) {
        int ko_ = ks*32 + quad*8;
        bf16x8 pah = *(const bf16x8*)&PH[(w*16 + mrow)*72 + ko_];
        bf16x8 pall = *(const bf16x8*)&PL[(w*16 + mrow)*72 + ko_];
        bf16x8 vh = *(const bf16x8*)&VH[(nt*16 + mrow)*72 + ko_];
        bf16x8 vl = *(const bf16x8*)&VL[(nt*16 + mrow)*72 + ko_];
        c = __builtin_amdgcn_mfma_f32_16x16x32_bf16(pah, vh, c, 0, 0, 0);
        c = __builtin_amdgcn_mfma_f32_16x16x32_bf16(pall, vh, c, 0, 0, 0);
        c = __builtin_amdgcn_mfma_f32_16x16x32_bf16(pah, vl, c, 0, 0, 0);
      }
      O_[nt][0] = c.x; O_[nt][1] = c.y; O_[nt][2] = c.z; O_[nt][3] = c.w;
    }
  }

  // ---- epilogue: normalize + store ----
  #pragma unroll
  for (int reg = 0; reg < 4; ++reg) {
    int rowg = qt*64 + w*16 + quad*4 + reg;
    if (rowg < T_) {
      float inv = 1.f / lsum[reg];
      #pragma unroll
      for (int nt = 0; nt < 4; ++nt) {
        out[((size_t)b*T_ + rowg)*H_ + nt*16 + mrow] = O_[nt][reg] * inv;
      }
    }
  }
}

extern "C" void kernel_launch(void* const* d_in, const int* in_sizes, int n_in,
                              void* d_out, int out_size, void* d_ws, size_t ws_size,
                              hipStream_t stream) {
  const float* x      = (const float*)d_in[0];
  const float* wq     = (const float*)d_in[1];
  const float* wk     = (const float*)d_in[2];
  const float* wv     = (const float*)d_in[3];
  const float* qg     = (const float*)d_in[4];
  const float* qb     = (const float*)d_in[5];
  const float* kg     = (const float*)d_in[6];
  const float* kb     = (const float*)d_in[7];
  const float* wsig   = (const float*)d_in[8];
  const float* bsig   = (const float*)d_in[9];
  const float* walp   = (const float*)d_in[10];
  const float* balp   = (const float*)d_in[11];
  float* out = (float*)d_out;

  float* ws  = (float*)d_ws;
  const size_t nrow = (size_t)B_ * T_;        // 36928
  float* qo  = ws;
  float* ko  = qo + nrow*H_;
  float* vo  = ko + nrow*H_;
  float* alo = vo + nrow*H_;
  float* sxo = alo + (size_t)B_*N_;
  float* syo = sxo + (size_t)B_*N_;
  __bf16* wsw_hi = (__bf16*)(syo + (size_t)B_*N_);
  __bf16* wsw_lo = wsw_hi + 24*192*32;

  hipLaunchKernelGGL(prep_w_kernel, dim3(576), dim3(256), 0, stream,
                     wq, wk, wv, wsw_hi, wsw_lo);
  hipLaunchKernelGGL(qkv_ln_kernel, dim3(577), dim3(256), 0, stream,
                     x, wsw_hi, wsw_lo, qg, qb, kg, kb, wsig, bsig, walp, balp,
                     qo, ko, vo, alo, sxo, syo);
  hipLaunchKernelGGL(attn_kernel, dim3(10, B_), dim3(256), 0, stream,
                     qo, ko, vo, alo, sxo, syo, out);
}

// Round 5
// 289.413 us; speedup vs baseline: 2.0245x; 1.0294x over previous
//
#include <hip/hip_runtime.h>
#include <math.h>

#define B_ 64
#define T_ 577
#define E_ 768
#define H_ 64
#define N_ 576
#define GW_ 24

typedef float f32x4 __attribute__((ext_vector_type(4)));
typedef __bf16 bf16x8 __attribute__((ext_vector_type(8)));
typedef __bf16 bf16x4 __attribute__((ext_vector_type(4)));

__device__ inline void split_bf16(float f, __bf16& h, __bf16& l) {
  h = (__bf16)f;
  l = (__bf16)(f - (float)h);
}

// -------------------- Kernel 0: W -> split-bf16, chunked transposed layout --------------------
// Thread t -> (kc = t/192, n = t%192); 32 coalesced column reads, contiguous 32-bf16 row write.
__global__ __launch_bounds__(256) void prep_w_kernel(
    const float* __restrict__ wq, const float* __restrict__ wk, const float* __restrict__ wv,
    __bf16* __restrict__ wsw_hi, __bf16* __restrict__ wsw_lo)
{
  int t = blockIdx.x * 256 + threadIdx.x;
  if (t >= 24*192) return;
  int kc = t / 192, n = t - (t/192)*192;
  const float* src = (n < 64) ? wq : ((n < 128) ? wk : wv);
  int nn = n & 63;
  __bf16 hbuf[32], lbuf[32];
  #pragma unroll
  for (int kk = 0; kk < 32; ++kk) {
    float f = src[(size_t)(kc*32 + kk)*64 + nn];
    split_bf16(f, hbuf[kk], lbuf[kk]);
  }
  size_t base = (size_t)t * 32;
  #pragma unroll
  for (int i = 0; i < 4; ++i) {
    *(bf16x8*)(wsw_hi + base + i*8) = *(bf16x8*)&hbuf[i*8];
    *(bf16x8*)(wsw_lo + base + i*8) = *(bf16x8*)&lbuf[i*8];
  }
}

// -------------------- Kernel 1: MFMA qkv + LN + alpha/sigma heads --------------------
// 577 blocks x 64 rows, 4 waves. Stage rows padded to 40 bf16 (20-bank stride, conflict-free b128).
// Register-prefetch pipeline: load chunk kc+1 while MFMA-ing chunk kc.
__global__ __launch_bounds__(256) void qkv_ln_kernel(
    const float* __restrict__ x,
    const __bf16* __restrict__ wsw_hi, const __bf16* __restrict__ wsw_lo,
    const float* __restrict__ qg, const float* __restrict__ qb,
    const float* __restrict__ kg, const float* __restrict__ kb,
    const float* __restrict__ wsig, const float* __restrict__ bsig,
    const float* __restrict__ walp, const float* __restrict__ balp,
    float* __restrict__ qo, float* __restrict__ ko, float* __restrict__ vo,
    float* __restrict__ alo, float* __restrict__ sxo, float* __restrict__ syo)
{
  __shared__ __align__(16) float smem[64*193 + 256];
  __bf16* A_hi = (__bf16*)smem;            // 64 x 40
  __bf16* A_lo = A_hi + 64*40;
  __bf16* B_hi = A_lo + 64*40;             // 192 x 40
  __bf16* B_lo = B_hi + 192*40;            // stage total 40960 B, aliased by Cs
  float (*Cs)[193] = (float (*)[193])smem;
  float* mu_q = smem + 64*193;
  float* rs_q = mu_q + 64;
  float* mu_k = rs_q + 64;
  float* rs_k = mu_k + 64;

  const int tid  = threadIdx.x;
  const int lane = tid & 63;
  const int w    = tid >> 6;
  const int rowbase = blockIdx.x << 6;

  f32x4 acc[4][3];
  #pragma unroll
  for (int mt = 0; mt < 4; ++mt)
    #pragma unroll
    for (int nt = 0; nt < 3; ++nt)
      acc[mt][nt] = (f32x4){0.f, 0.f, 0.f, 0.f};

  const int m     = lane & 15;
  const int kfrag = (lane >> 4) * 8;

  // prefetch registers
  float4 xr0, xr1;
  bf16x8 whr[3], wlr[3];
  const int s0 = tid, s1 = tid + 256;
  const int arow0 = s0 >> 3, ak0 = (s0 & 7) * 4;
  const int arow1 = s1 >> 3, ak1 = (s1 & 7) * 4;

  auto load_chunk = [&](int kc) {
    xr0 = *(const float4*)(x + (size_t)(rowbase + arow0)*E_ + kc*32 + ak0);
    xr1 = *(const float4*)(x + (size_t)(rowbase + arow1)*E_ + kc*32 + ak1);
    #pragma unroll
    for (int i = 0; i < 3; ++i) {
      int e = tid + 256*i;
      whr[i] = *(const bf16x8*)(wsw_hi + (size_t)kc*6144 + e*8);
      wlr[i] = *(const bf16x8*)(wsw_lo + (size_t)kc*6144 + e*8);
    }
  };
  auto store_chunk = [&]() {
    __bf16 h0,l0,h1,l1,h2,l2,h3,l3;
    split_bf16(xr0.x,h0,l0); split_bf16(xr0.y,h1,l1);
    split_bf16(xr0.z,h2,l2); split_bf16(xr0.w,h3,l3);
    *(bf16x4*)&A_hi[arow0*40 + ak0] = (bf16x4){h0,h1,h2,h3};
    *(bf16x4*)&A_lo[arow0*40 + ak0] = (bf16x4){l0,l1,l2,l3};
    split_bf16(xr1.x,h0,l0); split_bf16(xr1.y,h1,l1);
    split_bf16(xr1.z,h2,l2); split_bf16(xr1.w,h3,l3);
    *(bf16x4*)&A_hi[arow1*40 + ak1] = (bf16x4){h0,h1,h2,h3};
    *(bf16x4*)&A_lo[arow1*40 + ak1] = (bf16x4){l0,l1,l2,l3};
    #pragma unroll
    for (int i = 0; i < 3; ++i) {
      int e = tid + 256*i;
      int n = e >> 2, g = e & 3;
      *(bf16x8*)&B_hi[n*40 + g*8] = whr[i];
      *(bf16x8*)&B_lo[n*40 + g*8] = wlr[i];
    }
  };

  load_chunk(0);
  #pragma unroll 1
  for (int kc = 0; kc < 24; ++kc) {
    __syncthreads();          // previous chunk's LDS consumers done
    store_chunk();
    __syncthreads();
    if (kc < 23) load_chunk(kc + 1);   // overlap with MFMA below

    bf16x8 bh[3], bl[3];
    #pragma unroll
    for (int nt = 0; nt < 3; ++nt) {
      int n = w*48 + nt*16 + m;
      bh[nt] = *(const bf16x8*)&B_hi[n*40 + kfrag];
      bl[nt] = *(const bf16x8*)&B_lo[n*40 + kfrag];
    }
    #pragma unroll
    for (int mt = 0; mt < 4; ++mt) {
      bf16x8 ah = *(const bf16x8*)&A_hi[(mt*16 + m)*40 + kfrag];
      bf16x8 al = *(const bf16x8*)&A_lo[(mt*16 + m)*40 + kfrag];
      #pragma unroll
      for (int nt = 0; nt < 3; ++nt) {
        acc[mt][nt] = __builtin_amdgcn_mfma_f32_16x16x32_bf16(ah, bh[nt], acc[mt][nt], 0, 0, 0);
        acc[mt][nt] = __builtin_amdgcn_mfma_f32_16x16x32_bf16(al, bh[nt], acc[mt][nt], 0, 0, 0);
        acc[mt][nt] = __builtin_amdgcn_mfma_f32_16x16x32_bf16(ah, bl[nt], acc[mt][nt], 0, 0, 0);
      }
    }
  }
  __syncthreads();   // all LDS frag reads done before aliasing as C tile

  #pragma unroll
  for (int mt = 0; mt < 4; ++mt)
    #pragma unroll
    for (int nt = 0; nt < 3; ++nt) {
      int row = mt*16 + (lane >> 4)*4;
      int col = w*48 + nt*16 + (lane & 15);
      Cs[row + 0][col] = acc[mt][nt].x;
      Cs[row + 1][col] = acc[mt][nt].y;
      Cs[row + 2][col] = acc[mt][nt].z;
      Cs[row + 3][col] = acc[mt][nt].w;
    }
  __syncthreads();

  // stats: wave0 -> q rows, wave1 -> k rows (parallel)
  if (tid < 64) {
    float s = 0.f;
    for (int h = 0; h < 64; ++h) s += Cs[tid][h];
    float mu = s * (1.f/64.f);
    float vs = 0.f;
    for (int h = 0; h < 64; ++h) { float d = Cs[tid][h] - mu; vs += d*d; }
    mu_q[tid] = mu;
    rs_q[tid] = rsqrtf(vs*(1.f/64.f) + 1e-5f);
  } else if (tid < 128) {
    int r = tid - 64;
    float s = 0.f;
    for (int h = 0; h < 64; ++h) s += Cs[r][64+h];
    float mu = s * (1.f/64.f);
    float vs = 0.f;
    for (int h = 0; h < 64; ++h) { float d = Cs[r][64+h] - mu; vs += d*d; }
    mu_k[r] = mu;
    rs_k[r] = rsqrtf(vs*(1.f/64.f) + 1e-5f);
  }
  __syncthreads();

  // heads on wave 3 (rows = tid-192), LN-apply on everyone
  if (tid >= 192) {
    int r = tid - 192;
    int mrow = rowbase + r;
    int tindex = mrow % T_;
    if (tindex >= 1) {
      int bb = mrow / T_;
      int g = tindex - 1;
      float mu = mu_q[r], rs = rs_q[r];
      float za = 0.f, z0 = 0.f, z1 = 0.f;
      for (int h = 0; h < 64; ++h) {
        float qv = (Cs[r][h] - mu) * rs * qg[h] + qb[h];
        za += qv * walp[h];
        z0 += qv * wsig[2*h];
        z1 += qv * wsig[2*h+1];
      }
      za += balp[0]; z0 += bsig[0]; z1 += bsig[1];
      float al = fmaxf(za, 0.f) + log1pf(__expf(-fabsf(za)));
      float sx = 1.f/(1.f + __expf(-z0));
      float sy = 1.f/(1.f + __expf(-z1));
      alo[bb*N_ + g] = al;
      sxo[bb*N_ + g] = 0.5f/(sx*sx);
      syo[bb*N_ + g] = 0.5f/(sy*sy);
    }
  }
  // LN-apply + store q,k,v (float4 per thread-iteration)
  for (int idx = tid; idx < 64*48; idx += 256) {
    int r = idx / 48, c4 = (idx - (idx/48)*48) * 4;
    size_t row = (size_t)rowbase + r;
    float4 val = make_float4(Cs[r][c4], Cs[r][c4+1], Cs[r][c4+2], Cs[r][c4+3]);
    if (c4 < 64) {
      float mu = mu_q[r], rs = rs_q[r];
      float4 o;
      o.x = (val.x - mu)*rs*qg[c4+0] + qb[c4+0];
      o.y = (val.y - mu)*rs*qg[c4+1] + qb[c4+1];
      o.z = (val.z - mu)*rs*qg[c4+2] + qb[c4+2];
      o.w = (val.w - mu)*rs*qg[c4+3] + qb[c4+3];
      *(float4*)(qo + row*64 + c4) = o;
    } else if (c4 < 128) {
      int h = c4 - 64;
      float mu = mu_k[r], rs = rs_k[r];
      float4 o;
      o.x = (val.x - mu)*rs*kg[h+0] + kb[h+0];
      o.y = (val.y - mu)*rs*kg[h+1] + kb[h+1];
      o.z = (val.z - mu)*rs*kg[h+2] + kb[h+2];
      o.w = (val.w - mu)*rs*kg[h+3] + kb[h+3];
      *(float4*)(ko + row*64 + h) = o;
    } else {
      *(float4*)(vo + row*64 + (c4-128)) = val;
    }
  }
}

// -------------------- Kernel 2: MFMA flash attention + Gaussian bias --------------------
// grid (10, 64): 64 q-rows/block, 4 waves; K/V register-prefetch pipeline across key tiles.
__global__ __launch_bounds__(256) void attn_kernel(
    const float* __restrict__ q, const float* __restrict__ k, const float* __restrict__ v,
    const float* __restrict__ ala, const float* __restrict__ sxa, const float* __restrict__ sya,
    float* __restrict__ out)
{
  __shared__ __align__(16) __bf16 sm[8*4608];   // 8 regions of 64x72
  __shared__ float prm_al[64], prm_sx[64], prm_sy[64], prm_gr[64], prm_gc[64];
  __shared__ int   prm_has[64];

  __bf16* QH = sm;            __bf16* QL = sm + 4608;
  __bf16* KH = sm + 2*4608;   __bf16* KL = sm + 3*4608;
  __bf16* VH = sm + 4*4608;   __bf16* VL = sm + 5*4608;   // V^T: [dim][key]
  __bf16* PH = sm + 6*4608;   __bf16* PL = sm + 7*4608;

  const int tid  = threadIdx.x;
  const int lane = tid & 63;
  const int w    = tid >> 6;
  const int quad = lane >> 4;
  const int mrow = lane & 15;
  const int b    = blockIdx.y;
  const int qt   = blockIdx.x;

  const float* qbase = q + (size_t)b * T_ * H_;
  const float* kbase = k + (size_t)b * T_ * H_;
  const float* vbase = v + (size_t)b * T_ * H_;

  if (tid < 64) {
    int row = qt*64 + tid;
    float al=0.f, isx=0.f, isy=0.f, gr=0.f, gc=0.f; int has = 0;
    if (row >= 1 && row < T_) {
      int g = row - 1;
      al  = ala[b*N_ + g] * 0.125f;
      isx = sxa[b*N_ + g];
      isy = sya[b*N_ + g];
      gr  = (float)(g / GW_);
      gc  = (float)(g - (g/GW_)*GW_);
      has = 1;
    }
    prm_al[tid]=al; prm_sx[tid]=isx; prm_sy[tid]=isy;
    prm_gr[tid]=gr; prm_gc[tid]=gc; prm_has[tid]=has;
  }
  #pragma unroll
  for (int i = 0; i < 4; ++i) {
    int s = tid + 256*i;
    int r = s >> 4, c4 = (s & 15)*4;
    int row = qt*64 + r;
    int rowc = row < T_ ? row : T_ - 1;
    float4 v4 = *(const float4*)(qbase + (size_t)rowc*H_ + c4);
    v4.x *= 0.125f; v4.y *= 0.125f; v4.z *= 0.125f; v4.w *= 0.125f;
    __bf16 h0,l0,h1,l1,h2,l2,h3,l3;
    split_bf16(v4.x,h0,l0); split_bf16(v4.y,h1,l1);
    split_bf16(v4.z,h2,l2); split_bf16(v4.w,h3,l3);
    *(bf16x4*)&QH[r*72 + c4] = (bf16x4){h0,h1,h2,h3};
    *(bf16x4*)&QL[r*72 + c4] = (bf16x4){l0,l1,l2,l3};
  }
  __syncthreads();

  float p_al[4], p_sx[4], p_sy[4], p_gr[4], p_gc[4]; int p_has[4];
  #pragma unroll
  for (int reg = 0; reg < 4; ++reg) {
    int rr = w*16 + quad*4 + reg;
    p_al[reg]=prm_al[rr]; p_sx[reg]=prm_sx[rr]; p_sy[reg]=prm_sy[rr];
    p_gr[reg]=prm_gr[rr]; p_gc[reg]=prm_gc[rr]; p_has[reg]=prm_has[rr];
  }

  float mo[4], lsum[4], O_[4][4];
  #pragma unroll
  for (int reg = 0; reg < 4; ++reg) { mo[reg] = -INFINITY; lsum[reg] = 0.f; }
  #pragma unroll
  for (int nt = 0; nt < 4; ++nt)
    #pragma unroll
    for (int reg = 0; reg < 4; ++reg) O_[nt][reg] = 0.f;

  // K/V prefetch registers
  float4 kreg[4];
  float  vreg[16];
  const int d0 = tid & 15, k0 = (tid >> 4) * 4;

  auto load_kv = [&](int kt) {
    #pragma unroll
    for (int i = 0; i < 4; ++i) {
      int s = tid + 256*i;
      int key = s >> 4, c4 = (s & 15)*4;
      int kgl = kt*64 + key;
      int kcl = kgl < T_ ? kgl : T_ - 1;
      kreg[i] = *(const float4*)(kbase + (size_t)kcl*H_ + c4);
    }
    #pragma unroll
    for (int di = 0; di < 4; ++di)
      #pragma unroll
      for (int ki = 0; ki < 4; ++ki) {
        int kgl = kt*64 + k0 + ki;
        int kcl = kgl < T_ ? kgl : T_ - 1;
        vreg[di*4+ki] = vbase[(size_t)kcl*H_ + d0 + 16*di];
      }
  };
  auto store_kv = [&]() {
    #pragma unroll
    for (int i = 0; i < 4; ++i) {
      int s = tid + 256*i;
      int key = s >> 4, c4 = (s & 15)*4;
      __bf16 h0,l0,h1,l1,h2,l2,h3,l3;
      split_bf16(kreg[i].x,h0,l0); split_bf16(kreg[i].y,h1,l1);
      split_bf16(kreg[i].z,h2,l2); split_bf16(kreg[i].w,h3,l3);
      *(bf16x4*)&KH[key*72 + c4] = (bf16x4){h0,h1,h2,h3};
      *(bf16x4*)&KL[key*72 + c4] = (bf16x4){l0,l1,l2,l3};
    }
    #pragma unroll
    for (int di = 0; di < 4; ++di) {
      int dim = d0 + 16*di;
      __bf16 h0,l0,h1,l1,h2,l2,h3,l3;
      split_bf16(vreg[di*4+0],h0,l0); split_bf16(vreg[di*4+1],h1,l1);
      split_bf16(vreg[di*4+2],h2,l2); split_bf16(vreg[di*4+3],h3,l3);
      *(bf16x4*)&VH[dim*72 + k0] = (bf16x4){h0,h1,h2,h3};
      *(bf16x4*)&VL[dim*72 + k0] = (bf16x4){l0,l1,l2,l3};
    }
  };

  load_kv(0);
  #pragma unroll 1
  for (int kt = 0; kt < 10; ++kt) {
    __syncthreads();
    store_kv();
    __syncthreads();
    if (kt < 9) load_kv(kt + 1);   // overlap with compute below

    // ---- S = (Q/8)·K^T ----
    float S_[4][4];
    {
      f32x4 sac[4];
      #pragma unroll
      for (int nt = 0; nt < 4; ++nt) sac[nt] = (f32x4){0.f,0.f,0.f,0.f};
      #pragma unroll
      for (int ks = 0; ks < 2; ++ks) {
        int ko_ = ks*32 + quad*8;
        bf16x8 qh = *(const bf16x8*)&QH[(w*16 + mrow)*72 + ko_];
        bf16x8 ql = *(const bf16x8*)&QL[(w*16 + mrow)*72 + ko_];
        #pragma unroll
        for (int nt = 0; nt < 4; ++nt) {
          bf16x8 kh = *(const bf16x8*)&KH[(nt*16 + mrow)*72 + ko_];
          bf16x8 kl = *(const bf16x8*)&KL[(nt*16 + mrow)*72 + ko_];
          sac[nt] = __builtin_amdgcn_mfma_f32_16x16x32_bf16(qh, kh, sac[nt], 0, 0, 0);
          sac[nt] = __builtin_amdgcn_mfma_f32_16x16x32_bf16(ql, kh, sac[nt], 0, 0, 0);
          sac[nt] = __builtin_amdgcn_mfma_f32_16x16x32_bf16(qh, kl, sac[nt], 0, 0, 0);
        }
      }
      #pragma unroll
      for (int nt = 0; nt < 4; ++nt) {
        S_[nt][0] = sac[nt].x; S_[nt][1] = sac[nt].y;
        S_[nt][2] = sac[nt].z; S_[nt][3] = sac[nt].w;
      }
    }

    // ---- Gaussian bias + masking ----
    #pragma unroll
    for (int nt = 0; nt < 4; ++nt) {
      int keyg = kt*64 + nt*16 + mrow;
      bool kval = keyg < T_;
      bool khas = (keyg >= 1) && kval;
      float kgf = (float)(keyg - 1);
      float krf = floorf(kgf * (1.0f/24.0f));
      float kcf = kgf - 24.f*krf;
      #pragma unroll
      for (int reg = 0; reg < 4; ++reg) {
        float sval = S_[nt][reg];
        float dx = p_gc[reg] - kcf, dy = p_gr[reg] - krf;
        float bias = p_al[reg] * __expf(-(dx*dx*p_sx[reg] + dy*dy*p_sy[reg]));
        sval += (khas && p_has[reg]) ? bias : 0.f;
        S_[nt][reg] = kval ? sval : -1e30f;
      }
    }

    // ---- online softmax (16-lane reductions) ----
    float lt_[4], sc_[4], mn_[4];
    #pragma unroll
    for (int reg = 0; reg < 4; ++reg) {
      float mx = fmaxf(fmaxf(S_[0][reg], S_[1][reg]), fmaxf(S_[2][reg], S_[3][reg]));
      mx = fmaxf(mx, __shfl_xor(mx, 1, 64));
      mx = fmaxf(mx, __shfl_xor(mx, 2, 64));
      mx = fmaxf(mx, __shfl_xor(mx, 4, 64));
      mx = fmaxf(mx, __shfl_xor(mx, 8, 64));
      mn_[reg] = fmaxf(mo[reg], mx);
      lt_[reg] = 0.f;
    }
    #pragma unroll
    for (int nt = 0; nt < 4; ++nt)
      #pragma unroll
      for (int reg = 0; reg < 4; ++reg) {
        float p = __expf(S_[nt][reg] - mn_[reg]);
        S_[nt][reg] = p;
        lt_[reg] += p;
      }
    #pragma unroll
    for (int reg = 0; reg < 4; ++reg) {
      float ls = lt_[reg];
      ls += __shfl_xor(ls, 1, 64);
      ls += __shfl_xor(ls, 2, 64);
      ls += __shfl_xor(ls, 4, 64);
      ls += __shfl_xor(ls, 8, 64);
      sc_[reg] = __expf(mo[reg] - mn_[reg]);
      lsum[reg] = lsum[reg]*sc_[reg] + ls;
      mo[reg] = mn_[reg];
    }
    #pragma unroll
    for (int nt = 0; nt < 4; ++nt)
      #pragma unroll
      for (int reg = 0; reg < 4; ++reg) O_[nt][reg] *= sc_[reg];

    // ---- pack P (hi/lo) into per-wave band; same-wave RAW ----
    #pragma unroll
    for (int nt = 0; nt < 4; ++nt)
      #pragma unroll
      for (int reg = 0; reg < 4; ++reg) {
        float p = S_[nt][reg];
        __bf16 ph, pl;
        split_bf16(p, ph, pl);
        int addr = (w*16 + quad*4 + reg)*72 + nt*16 + mrow;
        PH[addr] = ph;
        PL[addr] = pl;
      }

    // ---- O += P·V ----
    #pragma unroll
    for (int nt = 0; nt < 4; ++nt) {
      f32x4 c = (f32x4){O_[nt][0], O_[nt][1], O_[nt][2], O_[nt][3]};
      #pragma unroll
      for (int ks = 0; ks < 2; ++ks) {
        int ko_ = ks*32 + quad*8;
        bf16x8 pah  = *(const bf16x8*)&PH[(w*16 + mrow)*72 + ko_];
        bf16x8 pall = *(const bf16x8*)&PL[(w*16 + mrow)*72 + ko_];
        bf16x8 vh   = *(const bf16x8*)&VH[(nt*16 + mrow)*72 + ko_];
        bf16x8 vl   = *(const bf16x8*)&VL[(nt*16 + mrow)*72 + ko_];
        c = __builtin_amdgcn_mfma_f32_16x16x32_bf16(pah, vh, c, 0, 0, 0);
        c = __builtin_amdgcn_mfma_f32_16x16x32_bf16(pall, vh, c, 0, 0, 0);
        c = __builtin_amdgcn_mfma_f32_16x16x32_bf16(pah, vl, c, 0, 0, 0);
      }
      O_[nt][0] = c.x; O_[nt][1] = c.y; O_[nt][2] = c.z; O_[nt][3] = c.w;
    }
  }

  #pragma unroll
  for (int reg = 0; reg < 4; ++reg) {
    int rowg = qt*64 + w*16 + quad*4 + reg;
    if (rowg < T_) {
      float inv = 1.f / lsum[reg];
      #pragma unroll
      for (int nt = 0; nt < 4; ++nt) {
        out[((size_t)b*T_ + rowg)*H_ + nt*16 + mrow] = O_[nt][reg] * inv;
      }
    }
  }
}

extern "C" void kernel_launch(void* const* d_in, const int* in_sizes, int n_in,
                              void* d_out, int out_size, void* d_ws, size_t ws_size,
                              hipStream_t stream) {
  const float* x      = (const float*)d_in[0];
  const float* wq     = (const float*)d_in[1];
  const float* wk     = (const float*)d_in[2];
  const float* wv     = (const float*)d_in[3];
  const float* qg     = (const float*)d_in[4];
  const float* qb     = (const float*)d_in[5];
  const float* kg     = (const float*)d_in[6];
  const float* kb     = (const float*)d_in[7];
  const float* wsig   = (const float*)d_in[8];
  const float* bsig   = (const float*)d_in[9];
  const float* walp   = (const float*)d_in[10];
  const float* balp   = (const float*)d_in[11];
  float* out = (float*)d_out;

  float* ws  = (float*)d_ws;
  const size_t nrow = (size_t)B_ * T_;        // 36928
  float* qo  = ws;
  float* ko  = qo + nrow*H_;
  float* vo  = ko + nrow*H_;
  float* alo = vo + nrow*H_;
  float* sxo = alo + (size_t)B_*N_;
  float* syo = sxo + (size_t)B_*N_;
  __bf16* wsw_hi = (__bf16*)(syo + (size_t)B_*N_);
  __bf16* wsw_lo = wsw_hi + 24*192*32;

  hipLaunchKernelGGL(prep_w_kernel, dim3(18), dim3(256), 0, stream,
                     wq, wk, wv, wsw_hi, wsw_lo);
  hipLaunchKernelGGL(qkv_ln_kernel, dim3(577), dim3(256), 0, stream,
                     x, wsw_hi, wsw_lo, qg, qb, kg, kb, wsig, bsig, walp, balp,
                     qo, ko, vo, alo, sxo, syo);
  hipLaunchKernelGGL(attn_kernel, dim3(10, B_), dim3(256), 0, stream,
                     qo, ko, vo, alo, sxo, syo, out);
}